// Round 9
// baseline (385.396 us; speedup 1.0000x reference)
//
#include <hip/hip_runtime.h>
#include <stdint.h>

// ---------------- problem dims ----------------
#define B_DIM 64
#define P_DIM 225
#define K_DIM 16
#define D_DIM 640
#define M_REAL (B_DIM * P_DIM)   // 14400 query rows
#define N_REAL (K_DIM * P_DIM)   // 3600 reference rows

// ---------------- GEMM tiling ----------------
#define BM 128
#define BN 128
#define MTILES 113               // ceil(14400/128) -> Mpad 14464
#define NTILES 29                // ceil(3600/128)  -> Npad 3712
#define MPAD (MTILES * BM)
#define NPAD (NTILES * BN)
#define MCHUNK 15                // ceil(MTILES/8) per-XCD bm groups

typedef float f32x4 __attribute__((ext_vector_type(4)));
typedef int   v4i   __attribute__((ext_vector_type(4)));
typedef int   v8i   __attribute__((ext_vector_type(8)));
typedef float f32x16 __attribute__((ext_vector_type(16)));

// ---------------- helpers ----------------
// float -> OCP e4m3 byte (v_cvt_pk_fp8_f32)
__device__ __forceinline__ unsigned char f2fp8(float f) {
  int r = __builtin_amdgcn_cvt_pk_fp8_f32(f, f, 0, false);
  return (unsigned char)(r & 0xFF);
}

// monotone float -> uint key (order-preserving), for atomicMax on floats
__device__ __forceinline__ unsigned f2key(float f) {
  union { float f; unsigned u; } v; v.f = f;
  unsigned u = v.u;
  return (u & 0x80000000u) ? ~u : (u | 0x80000000u);
}
__device__ __forceinline__ float key2f(unsigned k) {
  unsigned b = (k & 0x80000000u) ? (k ^ 0x80000000u) : ~k;
  union { unsigned u; float f; } v; v.u = b;
  return v.f;
}

__device__ __forceinline__ void gl_lds16(const void* g, void* l) {
  __builtin_amdgcn_global_load_lds(
      (const __attribute__((address_space(1))) void*)g,
      (__attribute__((address_space(3))) void*)l,
      16, 0, 0);
}

__device__ __forceinline__ float sigmoidf(float x) {
  return 1.f / (1.f + expf(-x));
}

// =====================================================================
// Kernel A: staging (fp8 e4m3 outputs) — unchanged from round 8
// =====================================================================
#define QBLKS (MPAD / 4)
#define RBLKS (NPAD / 4)
#define ABLKS 16
__global__ __launch_bounds__(256) void stage_all_kernel(
    const float* __restrict__ q, const float* __restrict__ r,
    const float* __restrict__ r_img, const float* __restrict__ aw1,
    unsigned char* __restrict__ qb, unsigned char* __restrict__ rb,
    float* __restrict__ qinv, unsigned* __restrict__ rowmax,
    float* __restrict__ h1) {
  const int blk = blockIdx.x;
  const int tid = threadIdx.x;

  if (blk < ABLKS) {
    __shared__ float rk_s[D_DIM];
    const int k = blk;
    for (int i = tid; i < D_DIM; i += 256) rk_s[i] = r_img[k * D_DIM + i];
    __syncthreads();
    if (tid < 160) {
      const int j = tid;
      float a = 0.f;
#pragma unroll 8
      for (int d = 0; d < D_DIM; d++) a += rk_s[d] * aw1[d * 160 + j];
      h1[k * 160 + j] = fmaxf(a, 0.f);
    }
    return;
  }

  if (blk < ABLKS + QBLKS) {
    int row = (blk - ABLKS) * 4 + (tid >> 6);
    int lane = tid & 63;
    if (lane == 0) rowmax[row] = 0u;
    unsigned char* dst = qb + (long)row * D_DIM;
    if (row >= M_REAL) {
#pragma unroll
      for (int i = 0; i < 10; i++) dst[i * 64 + lane] = 0;
      return;
    }
    const float* src = q + (long)row * D_DIM;
    float v[10];
    float ss = 0.f;
#pragma unroll
    for (int i = 0; i < 10; i++) { v[i] = src[i * 64 + lane]; ss += v[i] * v[i]; }
#pragma unroll
    for (int off = 32; off > 0; off >>= 1) ss += __shfl_xor(ss, off);
    float inv = 1.f / (sqrtf(ss) + 1e-6f);
    if (lane == 0) qinv[row] = inv * (1.f / 16.f);  // fold r-scale
#pragma unroll
    for (int i = 0; i < 10; i++) dst[i * 64 + lane] = f2fp8(v[i]);
    return;
  }

  {
    int row = (blk - ABLKS - QBLKS) * 4 + (tid >> 6);
    int lane = tid & 63;
    unsigned char* dst = rb + (long)row * D_DIM;
    if (row >= N_REAL) {
#pragma unroll
      for (int i = 0; i < 10; i++) dst[i * 64 + lane] = 0;
      return;
    }
    const float* src = r + (long)row * D_DIM;
    float v[10];
    float ss = 0.f;
#pragma unroll
    for (int i = 0; i < 10; i++) { v[i] = src[i * 64 + lane]; ss += v[i] * v[i]; }
#pragma unroll
    for (int off = 32; off > 0; off >>= 1) ss += __shfl_xor(ss, off);
    float sc = 16.f / (sqrtf(ss) + 1e-6f);   // normalize, x16 into e4m3 normals
#pragma unroll
    for (int i = 0; i < 10; i++) dst[i * 64 + lane] = f2fp8(v[i] * sc);
  }
}

// =====================================================================
// Kernel B: fused MX-fp8 MFMA GEMM + row-max.
//   mfma_scale_f32_32x32x64_f8f6f4, unit scales (0x7F = 2^0) — math
//   identical to non-scaled fp8, 2x the FLOP/cycle (m148/m59).
//   Per wave: 2x2 tiles of 32x32; BK=128 per iter (two K=64 halves),
//   5 iters, 8 MFMA + 16 ds_read_b128 per wave per iter.
//   LDS per half: [4 row-groups][4 planes][32 rows][16 B] (chunk-planar):
//   reader slot = g*128 + kh*64 + r (+32 for 2nd chunk) -> bank r mod 8
//   per 8-lane group: conflict-free. Staging: base + lane*16 contiguous.
// =====================================================================
__global__ __launch_bounds__(256) void sim_max_kernel(
    const unsigned char* __restrict__ Qb,
    const unsigned char* __restrict__ Rb,
    unsigned* __restrict__ rowmax) {
  __shared__ __attribute__((aligned(16))) unsigned char As[2][8192];  // 2x8 KB
  __shared__ __attribute__((aligned(16))) unsigned char Bs[2][8192];  // 2x8 KB

  const int xcd = blockIdx.x & 7;
  const int idx = blockIdx.x >> 3;
  const int bm = xcd + 8 * (idx % MCHUNK);
  const int bn = idx / MCHUNK;
  if (bm >= MTILES) return;

  const int tid = threadIdx.x;
  const int lane = tid & 63;
  const int wave = tid >> 6;
  const int wr = wave >> 1, wc = wave & 1;
  const int r32 = lane & 31, kh = lane >> 5;

  // staging slots: s0 = tid, s1 = tid + 256 (per operand per K-half).
  // slot s -> row (s>>7)*32 + (s&31), byte-in-64B-row ((s>>5)&3)*16
  const int s0 = tid, s1 = tid + 256;
  const int row0 = ((s0 >> 7) << 5) | (s0 & 31);
  const int byt0 = ((s0 >> 5) & 3) * 16;
  const int row1 = ((s1 >> 7) << 5) | (s1 & 31);
  const int byt1 = ((s1 >> 5) & 3) * 16;

  const int aBase = bm * BM, bBase = bn * BN;

  f32x16 acc[2][2];
#pragma unroll
  for (int mi = 0; mi < 2; mi++)
#pragma unroll
    for (int ni = 0; ni < 2; ni++)
      acc[mi][ni] = (f32x16){0.f, 0.f, 0.f, 0.f, 0.f, 0.f, 0.f, 0.f,
                             0.f, 0.f, 0.f, 0.f, 0.f, 0.f, 0.f, 0.f};

  for (int k0 = 0; k0 < D_DIM; k0 += 128) {
#pragma unroll
    for (int h = 0; h < 2; h++) {
      const int kb = k0 + h * 64;
      gl_lds16(Qb + (size_t)(aBase + row0) * D_DIM + kb + byt0, &As[h][s0 * 16]);
      gl_lds16(Qb + (size_t)(aBase + row1) * D_DIM + kb + byt1, &As[h][s1 * 16]);
      gl_lds16(Rb + (size_t)(bBase + row0) * D_DIM + kb + byt0, &Bs[h][s0 * 16]);
      gl_lds16(Rb + (size_t)(bBase + row1) * D_DIM + kb + byt1, &Bs[h][s1 * 16]);
    }
    __syncthreads();  // drains vmcnt -> all LDS tiles ready

#pragma unroll
    for (int h = 0; h < 2; h++) {
      v8i af[2], bf[2];
#pragma unroll
      for (int mi = 0; mi < 2; mi++) {
        const int off = (((wr * 2 + mi) * 128) + kh * 64 + r32) * 16;
        v4i lo = *(const v4i*)&As[h][off];
        v4i hi = *(const v4i*)&As[h][off + 512];
        af[mi] = __builtin_shufflevector(lo, hi, 0, 1, 2, 3, 4, 5, 6, 7);
      }
#pragma unroll
      for (int ni = 0; ni < 2; ni++) {
        const int off = (((wc * 2 + ni) * 128) + kh * 64 + r32) * 16;
        v4i lo = *(const v4i*)&Bs[h][off];
        v4i hi = *(const v4i*)&Bs[h][off + 512];
        bf[ni] = __builtin_shufflevector(lo, hi, 0, 1, 2, 3, 4, 5, 6, 7);
      }
#pragma unroll
      for (int mi = 0; mi < 2; mi++)
#pragma unroll
        for (int ni = 0; ni < 2; ni++)
          acc[mi][ni] = __builtin_amdgcn_mfma_scale_f32_32x32x64_f8f6f4(
              af[mi], bf[ni], acc[mi][ni],
              0, 0,          // cbsz=fp8(A), blgp=fp8(B)
              0, 127,        // scale A: byte0 = 0x7F -> 2^0
              0, 127);       // scale B: byte0 = 0x7F -> 2^0
    }
    __syncthreads();  // protect LDS before next-iter overwrite
  }

  // epilogue: per-row max over this block's 128 columns, then atomicMax.
  // C/D 32x32 layout: col = lane&31, row = (reg&3) + 8*(reg>>2) + 4*kh.
  const int colBase = bn * BN + wc * 64;
#pragma unroll
  for (int mi = 0; mi < 2; mi++) {
#pragma unroll
    for (int reg = 0; reg < 16; reg++) {
      float v = -3.0e38f;
#pragma unroll
      for (int ni = 0; ni < 2; ni++) {
        bool valid = (colBase + ni * 32 + r32) < N_REAL;
        float x = valid ? acc[mi][ni][reg] : -3.0e38f;
        v = fmaxf(v, x);
      }
      v = fmaxf(v, __shfl_xor(v, 1));
      v = fmaxf(v, __shfl_xor(v, 2));
      v = fmaxf(v, __shfl_xor(v, 4));
      v = fmaxf(v, __shfl_xor(v, 8));
      v = fmaxf(v, __shfl_xor(v, 16));
      if (r32 == 0) {
        int row = bm * BM + wr * 64 + mi * 32 + (reg & 3) + 8 * (reg >> 2) + 4 * kh;
        atomicMax(&rowmax[row], f2key(v));
      }
    }
  }
}

// =====================================================================
// Kernel T1: tail part 1 (unchanged).
// =====================================================================
__global__ __launch_bounds__(256) void tail1_kernel(
    const float* __restrict__ h1, const float* __restrict__ aw2,
    const unsigned* __restrict__ rowmax, const float* __restrict__ qinv,
    const float* __restrict__ hw1, const float* __restrict__ hb1,
    const float* __restrict__ hg2, const float* __restrict__ hbe2,
    float* __restrict__ favg, float* __restrict__ h1m,
    float* __restrict__ amean) {
  __shared__ __attribute__((aligned(16))) float S[12800];  // 51.2 KB
  const int blk = blockIdx.x;
  const int tid = threadIdx.x;
  const int wave = tid >> 6, lane = tid & 63;

  if (blk < 10) {
    const int d0 = blk * 64;
#pragma unroll
    for (int i = 0; i < 10; i++) S[i * 256 + tid] = h1[i * 256 + tid];
#pragma unroll
    for (int c = 0; c < 10; c++) {
      int e = c * 256 + tid;
      int row = e >> 4, col16 = e & 15;
      gl_lds16((const char*)aw2 + (size_t)row * D_DIM * 4 + d0 * 4 + col16 * 16,
               (char*)&S[2560] + e * 16);
    }
    __syncthreads();

    const int d = tid & 63, kg = tid >> 6;
    float a0 = 0.f, a1 = 0.f, a2 = 0.f, a3 = 0.f;
#pragma unroll 8
    for (int j = 0; j < 160; j++) {
      float w = S[2560 + j * 64 + d];
      a0 += S[(kg * 4 + 0) * 160 + j] * w;
      a1 += S[(kg * 4 + 1) * 160 + j] * w;
      a2 += S[(kg * 4 + 2) * 160 + j] * w;
      a3 += S[(kg * 4 + 3) * 160 + j] * w;
    }
    float p = fmaxf(a0, 0.f) + fmaxf(a1, 0.f) + fmaxf(a2, 0.f) + fmaxf(a3, 0.f);
    __syncthreads();
    S[kg * 64 + d] = p;
    __syncthreads();
    if (kg == 0)
      favg[d0 + d] = (S[d] + S[64 + d] + S[128 + d] + S[192 + d]) * (1.f / 16.f);
    return;
  }

  const int bO = (blk - 10) * 8;
  for (int e = tid; e < 8 * P_DIM; e += 256) {
    int row = bO * P_DIM + e;
    float mx = key2f(rowmax[row]);
    S[e] = 0.5f * (1.f - mx * qinv[row]);
  }
  __syncthreads();

#pragma unroll
  for (int i = 0; i < 2; i++) {
    int b = wave * 2 + i;
    float s = S[b * P_DIM + lane];
    s += S[b * P_DIM + lane + 64];
    s += S[b * P_DIM + lane + 128];
    if (lane < 33) s += S[b * P_DIM + lane + 192];
#pragma unroll
    for (int off = 32; off > 0; off >>= 1) s += __shfl_xor(s, off);
    if (lane == 0) amean[bO + b] = s * (1.f / 225.f);
  }

  const int j = tid & 127, bh = tid >> 7;
  float acc[4];
#pragma unroll
  for (int bb = 0; bb < 4; bb++) acc[bb] = hb1[j];

  for (int t = 0; t < 7; t++) {
    int p0 = t * 32;
#pragma unroll
    for (int c = 0; c < 4; c++) {
      int e = c * 256 + tid;
      int row = e >> 5, col16 = e & 31;
      gl_lds16((const char*)hw1 + (size_t)(p0 + row) * 128 * 4 + col16 * 16,
               (char*)&S[1800] + e * 16);
    }
    __syncthreads();
#pragma unroll 4
    for (int pr = 0; pr < 32; pr++) {
      float w = S[1800 + pr * 128 + j];
#pragma unroll
      for (int bb = 0; bb < 4; bb++)
        acc[bb] += S[(bh * 4 + bb) * P_DIM + p0 + pr] * w;
    }
    __syncthreads();
  }
  {
    float w = hw1[224 * 128 + j];
#pragma unroll
    for (int bb = 0; bb < 4; bb++)
      acc[bb] += S[(bh * 4 + bb) * P_DIM + 224] * w;
  }
#pragma unroll
  for (int bb = 0; bb < 4; bb++) {
    float h = fmaxf(acc[bb], 0.f) * hg2[j] + hbe2[j];
    h1m[(bO + bh * 4 + bb) * 128 + j] = h;
  }
}

// =====================================================================
// Kernel T2: tail part 2 (unchanged).
// =====================================================================
__global__ __launch_bounds__(256) void tail2_kernel(
    const float* __restrict__ q_img, const float* __restrict__ favg,
    const float* __restrict__ h1m, const float* __restrict__ amean,
    const float* __restrict__ hw2, const float* __restrict__ hb2,
    const float* __restrict__ hg3, const float* __restrict__ hbe3,
    const float* __restrict__ hw3, const float* __restrict__ hb3,
    const float* __restrict__ rw1, const float* __restrict__ rb1,
    const float* __restrict__ rg2, const float* __restrict__ rbe2,
    const float* __restrict__ rw2, const float* __restrict__ rb2,
    const float* __restrict__ rg3, const float* __restrict__ rbe3,
    const float* __restrict__ rw3, const float* __restrict__ rb3,
    float* __restrict__ out) {
  __shared__ __attribute__((aligned(16))) float S[14336];  // 57.3 KB
  const int tid = threadIdx.x;
  const int wave = tid >> 6, lane = tid & 63;
  const int bO = blockIdx.x * 8;

#pragma unroll
  for (int i = 0; i < 20; i++) {
    int e = i * 256 + tid;
    int d = e % D_DIM;
    S[e] = q_img[bO * D_DIM + e] - favg[d];
  }

#pragma unroll
  for (int c = 0; c < 4; c++) {
    int e = c * 256 + tid;
    int row = e >> 5, col16 = e & 31;
    gl_lds16((const char*)rw1 + (size_t)row * 128 * 4 + col16 * 16,
             (char*)&S[5120] + e * 16);
  }
  __syncthreads();

  const int j = tid & 127, bh = tid >> 7;
  float acc[4];
#pragma unroll
  for (int bb = 0; bb < 4; bb++) acc[bb] = rb1[j];

  for (int t = 0; t < 20; t++) {
    int bufC = 5120 + (t & 1) * 4096;
    int bufN = 5120 + ((t + 1) & 1) * 4096;
    if (t < 19) {
      int d0n = (t + 1) * 32;
#pragma unroll
      for (int c = 0; c < 4; c++) {
        int e = c * 256 + tid;
        int row = e >> 5, col16 = e & 31;
        gl_lds16((const char*)rw1 + (size_t)(d0n + row) * 128 * 4 + col16 * 16,
                 (char*)&S[bufN] + e * 16);
      }
    }
    int d0 = t * 32;
#pragma unroll 4
    for (int dr = 0; dr < 32; dr++) {
      float w = S[bufC + dr * 128 + j];
#pragma unroll
      for (int bb = 0; bb < 4; bb++)
        acc[bb] += S[(bh * 4 + bb) * D_DIM + d0 + dr] * w;
    }
    __syncthreads();
  }

#pragma unroll
  for (int bb = 0; bb < 4; bb++) {
    float h = fmaxf(acc[bb], 0.f) * rg2[j] + rbe2[j];
    S[13312 + (bh * 4 + bb) * 128 + j] = h;
  }
  __syncthreads();

#pragma unroll
  for (int c = 0; c < 8; c++) {
    int e = c * 256 + tid;
    gl_lds16((const char*)rw2 + e * 16, (char*)&S[0] + e * 16);
  }
#pragma unroll
  for (int i = 0; i < 4; i++) {
    int e = i * 256 + tid;
    S[8192 + e] = h1m[bO * 128 + e];
  }
  __syncthreads();

  {
    const int n = tid & 63, bg = tid >> 6;
#pragma unroll
    for (int bb = 0; bb < 2; bb++) {
      int b = bg * 2 + bb;
      float a = rb2[n];
#pragma unroll 8
      for (int jj = 0; jj < 128; jj++) a += S[13312 + b * 128 + jj] * S[jj * 64 + n];
      S[10240 + b * 64 + n] = fmaxf(a, 0.f) * rg3[n] + rbe3[n];
    }
  }
  __syncthreads();

#pragma unroll
  for (int c = 0; c < 8; c++) {
    int e = c * 256 + tid;
    gl_lds16((const char*)hw2 + e * 16, (char*)&S[0] + e * 16);
  }

#pragma unroll
  for (int i = 0; i < 2; i++) {
    int b = wave * 2 + i;
    float v = S[10240 + b * 64 + lane] * rw3[lane];
#pragma unroll
    for (int off = 32; off > 0; off >>= 1) v += __shfl_xor(v, off);
    if (lane == 0) S[11264 + b] = sigmoidf(v + rb3[0]);
  }
  __syncthreads();

  {
    const int n = tid & 63, bg = tid >> 6;
#pragma unroll
    for (int bb = 0; bb < 2; bb++) {
      int b = bg * 2 + bb;
      float a = hb2[n];
#pragma unroll 8
      for (int jj = 0; jj < 128; jj++) a += S[8192 + b * 128 + jj] * S[jj * 64 + n];
      S[10752 + b * 64 + n] = fmaxf(a, 0.f) * hg3[n] + hbe3[n];
    }
  }
  __syncthreads();

#pragma unroll
  for (int i = 0; i < 2; i++) {
    int b = wave * 2 + i;
    float v = S[10752 + b * 64 + lane] * hw3[lane];
#pragma unroll
    for (int off = 32; off > 0; off >>= 1) v += __shfl_xor(v, off);
    if (lane == 0) S[11272 + b] = sigmoidf(v + hb3[0]);
  }
  __syncthreads();

  if (tid < 8) {
    int b = bO + tid;
    out[b] = 0.5f * (S[11264 + tid] + S[11272 + tid]) + amean[b];
  }
}

// ---------------- launch ----------------
extern "C" void kernel_launch(void* const* d_in, const int* in_sizes, int n_in,
                              void* d_out, int out_size, void* d_ws, size_t ws_size,
                              hipStream_t stream) {
  const float* q_patch = (const float*)d_in[0];
  const float* r_patch = (const float*)d_in[1];
  const float* q_img   = (const float*)d_in[2];
  const float* r_img   = (const float*)d_in[3];
  const float* adpt_w1 = (const float*)d_in[4];
  const float* adpt_w2 = (const float*)d_in[5];
  const float* dh_w1 = (const float*)d_in[6];
  const float* dh_b1 = (const float*)d_in[7];
  const float* dh_g2 = (const float*)d_in[8];
  const float* dh_be2 = (const float*)d_in[9];
  const float* dh_w2 = (const float*)d_in[10];
  const float* dh_b2 = (const float*)d_in[11];
  const float* dh_g3 = (const float*)d_in[12];
  const float* dh_be3 = (const float*)d_in[13];
  const float* dh_w3 = (const float*)d_in[14];
  const float* dh_b3 = (const float*)d_in[15];
  const float* dr_w1 = (const float*)d_in[16];
  const float* dr_b1 = (const float*)d_in[17];
  const float* dr_g2 = (const float*)d_in[18];
  const float* dr_be2 = (const float*)d_in[19];
  const float* dr_w2 = (const float*)d_in[20];
  const float* dr_b2 = (const float*)d_in[21];
  const float* dr_g3 = (const float*)d_in[22];
  const float* dr_be3 = (const float*)d_in[23];
  const float* dr_w3 = (const float*)d_in[24];
  const float* dr_b3 = (const float*)d_in[25];

  // ws layout (bytes) — fp8 staging buffers
  const size_t QB_BYTES = (size_t)MPAD * D_DIM;   // 9,256,960
  const size_t RB_BYTES = (size_t)NPAD * D_DIM;   // 2,375,680
  char* ws = (char*)d_ws;
  unsigned char* qb = (unsigned char*)(ws);
  unsigned char* rb = (unsigned char*)(ws + QB_BYTES);
  float* qinv        = (float*)(ws + QB_BYTES + RB_BYTES);
  unsigned* rowmax   = (unsigned*)(ws + QB_BYTES + RB_BYTES + (size_t)M_REAL * 4);
  float* h1          = (float*)(ws + QB_BYTES + RB_BYTES + (size_t)M_REAL * 4 + (size_t)MPAD * 4);
  float* favg        = h1 + 16 * 160;
  float* h1m         = favg + D_DIM;
  float* amean       = h1m + 64 * 128;

  stage_all_kernel<<<ABLKS + QBLKS + RBLKS, 256, 0, stream>>>(
      q_patch, r_patch, r_img, adpt_w1, qb, rb, qinv, rowmax, h1);
  sim_max_kernel<<<8 * MCHUNK * NTILES, 256, 0, stream>>>(qb, rb, rowmax);
  tail1_kernel<<<18, 256, 0, stream>>>(
      h1, adpt_w2, rowmax, qinv, dh_w1, dh_b1, dh_g2, dh_be2,
      favg, h1m, amean);
  tail2_kernel<<<8, 256, 0, stream>>>(
      q_img, favg, h1m, amean,
      dh_w2, dh_b2, dh_g3, dh_be3, dh_w3, dh_b3,
      dr_w1, dr_b1, dr_g2, dr_be2, dr_w2, dr_b2, dr_g3, dr_be3, dr_w3, dr_b3,
      (float*)d_out);
}

// Round 10
// 290.370 us; speedup vs baseline: 1.3273x; 1.3273x over previous
//
#include <hip/hip_runtime.h>
#include <stdint.h>

// ---------------- problem dims ----------------
#define B_DIM 64
#define P_DIM 225
#define K_DIM 16
#define D_DIM 640
#define M_REAL (B_DIM * P_DIM)   // 14400 query rows
#define N_REAL (K_DIM * P_DIM)   // 3600 reference rows

// ---------------- GEMM tiling ----------------
#define BM 128
#define BN 128
#define MTILES 113               // ceil(14400/128) -> Mpad 14464
#define NTILES 29                // ceil(3600/128)  -> Npad 3712
#define MPAD (MTILES * BM)
#define NPAD (NTILES * BN)
#define MCHUNK 15                // ceil(MTILES/8) per-XCD bm groups

typedef float f32x4 __attribute__((ext_vector_type(4)));

// ---------------- helpers ----------------
// float -> OCP e4m3 byte (v_cvt_pk_fp8_f32)
__device__ __forceinline__ unsigned char f2fp8(float f) {
  int r = __builtin_amdgcn_cvt_pk_fp8_f32(f, f, 0, false);
  return (unsigned char)(r & 0xFF);
}

// monotone float -> uint key (order-preserving), for atomicMax on floats
__device__ __forceinline__ unsigned f2key(float f) {
  union { float f; unsigned u; } v; v.f = f;
  unsigned u = v.u;
  return (u & 0x80000000u) ? ~u : (u | 0x80000000u);
}
__device__ __forceinline__ float key2f(unsigned k) {
  unsigned b = (k & 0x80000000u) ? (k ^ 0x80000000u) : ~k;
  union { unsigned u; float f; } v; v.u = b;
  return v.f;
}

__device__ __forceinline__ void gl_lds16(const void* g, void* l) {
  __builtin_amdgcn_global_load_lds(
      (const __attribute__((address_space(1))) void*)g,
      (__attribute__((address_space(3))) void*)l,
      16, 0, 0);
}

__device__ __forceinline__ float sigmoidf(float x) {
  return 1.f / (1.f + expf(-x));
}

// =====================================================================
// Kernel A: staging (fp8 e4m3 outputs)
//   q rows: raw cast; qinv stores (1/16)/(||q||+eps)  [16 = r-scale]
//   r rows: L2-normalized then x16 (keeps e4m3 in normal range)
// =====================================================================
#define QBLKS (MPAD / 4)
#define RBLKS (NPAD / 4)
#define ABLKS 16
__global__ __launch_bounds__(256) void stage_all_kernel(
    const float* __restrict__ q, const float* __restrict__ r,
    const float* __restrict__ r_img, const float* __restrict__ aw1,
    unsigned char* __restrict__ qb, unsigned char* __restrict__ rb,
    float* __restrict__ qinv, unsigned* __restrict__ rowmax,
    float* __restrict__ h1) {
  const int blk = blockIdx.x;
  const int tid = threadIdx.x;

  if (blk < ABLKS) {
    __shared__ float rk_s[D_DIM];
    const int k = blk;
    for (int i = tid; i < D_DIM; i += 256) rk_s[i] = r_img[k * D_DIM + i];
    __syncthreads();
    if (tid < 160) {
      const int j = tid;
      float a = 0.f;
#pragma unroll 8
      for (int d = 0; d < D_DIM; d++) a += rk_s[d] * aw1[d * 160 + j];
      h1[k * 160 + j] = fmaxf(a, 0.f);
    }
    return;
  }

  if (blk < ABLKS + QBLKS) {
    int row = (blk - ABLKS) * 4 + (tid >> 6);
    int lane = tid & 63;
    if (lane == 0) rowmax[row] = 0u;
    unsigned char* dst = qb + (long)row * D_DIM;
    if (row >= M_REAL) {
#pragma unroll
      for (int i = 0; i < 10; i++) dst[i * 64 + lane] = 0;
      return;
    }
    const float* src = q + (long)row * D_DIM;
    float v[10];
    float ss = 0.f;
#pragma unroll
    for (int i = 0; i < 10; i++) { v[i] = src[i * 64 + lane]; ss += v[i] * v[i]; }
#pragma unroll
    for (int off = 32; off > 0; off >>= 1) ss += __shfl_xor(ss, off);
    float inv = 1.f / (sqrtf(ss) + 1e-6f);
    if (lane == 0) qinv[row] = inv * (1.f / 16.f);  // fold r-scale
#pragma unroll
    for (int i = 0; i < 10; i++) dst[i * 64 + lane] = f2fp8(v[i]);
    return;
  }

  {
    int row = (blk - ABLKS - QBLKS) * 4 + (tid >> 6);
    int lane = tid & 63;
    unsigned char* dst = rb + (long)row * D_DIM;
    if (row >= N_REAL) {
#pragma unroll
      for (int i = 0; i < 10; i++) dst[i * 64 + lane] = 0;
      return;
    }
    const float* src = r + (long)row * D_DIM;
    float v[10];
    float ss = 0.f;
#pragma unroll
    for (int i = 0; i < 10; i++) { v[i] = src[i * 64 + lane]; ss += v[i] * v[i]; }
#pragma unroll
    for (int off = 32; off > 0; off >>= 1) ss += __shfl_xor(ss, off);
    float sc = 16.f / (sqrtf(ss) + 1e-6f);   // normalize, x16 into e4m3 normals
#pragma unroll
    for (int i = 0; i < 10; i++) dst[i * 64 + lane] = f2fp8(v[i] * sc);
  }
}

// =====================================================================
// Kernel B: fused fp8 MFMA GEMM + row-max, chunk-planar LDS layout.
//   (round-8 optimum: 91.5 us, MfmaUtil 30.7%, conflicts at the free
//    2-way staging floor. Round 9's MX 32x32 variant regressed to
//    191 us via VGPR 160 / occupancy 10.6% — reverted.)
//   LDS tile = [8 groups][2 c][16 rows][16 B]: slot = g*32 + c*16 + rloc.
//   Frag read bank = (4*m0 + 2*h8) mod 32 -> all 32 banks, 2-way (free).
//   Staging permutes lanes only (still base+lane*16 contiguous in LDS).
// =====================================================================
__global__ __launch_bounds__(256) void sim_max_kernel(
    const unsigned char* __restrict__ Qb,
    const unsigned char* __restrict__ Rb,
    unsigned* __restrict__ rowmax) {
  __shared__ __attribute__((aligned(16))) unsigned char As[2][BM * 32];  // 2x4 KB
  __shared__ __attribute__((aligned(16))) unsigned char Bs[2][BN * 32];  // 2x4 KB

  const int xcd = blockIdx.x & 7;
  const int idx = blockIdx.x >> 3;
  const int bm = xcd + 8 * (idx % MCHUNK);
  const int bn = idx / MCHUNK;
  if (bm >= MTILES) return;

  const int tid = threadIdx.x;
  const int wave = tid >> 6, lane = tid & 63;
  const int wr = wave >> 1, wc = wave & 1;
  const int q = lane >> 4, m0 = lane & 15;
  const int cq = q >> 1, h8 = q & 1;   // 16-B chunk + 8-B half of frag

  // ---- staging geometry (chunk-planar): thread stages slot s = tid ----
  const int rS = ((tid >> 5) << 4) | (tid & 15);
  const int cS = (tid >> 4) & 1;
  const int f = tid * 16;              // LDS byte (contiguous, lane*16)

  // ---- frag read LDS byte offsets (within As[h]/Bs[h]) ----
  const int aG = wr * 4, bG = wc * 4;  // group base per wave
  const int fragBase = (cq * 16 + m0) * 16 + h8 * 8;

  const int aBase = bm * BM;
  const int bBase = bn * BN;

  f32x4 zero = {0.f, 0.f, 0.f, 0.f};
  f32x4 acc[4][4];
#pragma unroll
  for (int i = 0; i < 4; i++)
#pragma unroll
    for (int j = 0; j < 4; j++) acc[i][j] = zero;

  for (int k0 = 0; k0 < D_DIM; k0 += 64) {
#pragma unroll
    for (int h = 0; h < 2; h++) {
      gl_lds16(Qb + (size_t)(aBase + rS) * D_DIM + k0 + h * 32 + cS * 16, &As[h][f]);
      gl_lds16(Rb + (size_t)(bBase + rS) * D_DIM + k0 + h * 32 + cS * 16, &Bs[h][f]);
    }
    __syncthreads();  // drains vmcnt -> both LDS sub-tiles ready

#pragma unroll
    for (int h = 0; h < 2; h++) {
      long af[4], bfr[4];
#pragma unroll
      for (int mi = 0; mi < 4; mi++)
        af[mi] = *(const long*)&As[h][(aG + mi) * 512 + fragBase];
#pragma unroll
      for (int ni = 0; ni < 4; ni++)
        bfr[ni] = *(const long*)&Bs[h][(bG + ni) * 512 + fragBase];
#pragma unroll
      for (int mi = 0; mi < 4; mi++)
#pragma unroll
        for (int ni = 0; ni < 4; ni++)
          acc[mi][ni] = __builtin_amdgcn_mfma_f32_16x16x32_fp8_fp8(
              af[mi], bfr[ni], acc[mi][ni], 0, 0, 0);
    }
    __syncthreads();  // protect LDS before next-iter overwrite
  }

  // epilogue: per-row max over this block's 128 columns, then global atomicMax
  const int colBase = bn * BN + wc * 64;
#pragma unroll
  for (int mi = 0; mi < 4; mi++) {
    float rmax[4] = {-3.0e38f, -3.0e38f, -3.0e38f, -3.0e38f};
#pragma unroll
    for (int ni = 0; ni < 4; ni++) {
      bool valid = (colBase + ni * 16 + m0) < N_REAL;
#pragma unroll
      for (int r = 0; r < 4; r++) {
        float v = valid ? acc[mi][ni][r] : -3.0e38f;
        rmax[r] = fmaxf(rmax[r], v);
      }
    }
#pragma unroll
    for (int r = 0; r < 4; r++) {
      float v = rmax[r];
      v = fmaxf(v, __shfl_xor(v, 1));
      v = fmaxf(v, __shfl_xor(v, 2));
      v = fmaxf(v, __shfl_xor(v, 4));
      v = fmaxf(v, __shfl_xor(v, 8));
      rmax[r] = v;
    }
    if (m0 == 0) {
      int row = bm * BM + wr * 64 + mi * 16 + q * 4;
#pragma unroll
      for (int r = 0; r < 4; r++)
        atomicMax(&rowmax[row + r], f2key(rmax[r]));
    }
  }
}

// =====================================================================
// Kernel T1: tail part 1 (unchanged).
// =====================================================================
__global__ __launch_bounds__(256) void tail1_kernel(
    const float* __restrict__ h1, const float* __restrict__ aw2,
    const unsigned* __restrict__ rowmax, const float* __restrict__ qinv,
    const float* __restrict__ hw1, const float* __restrict__ hb1,
    const float* __restrict__ hg2, const float* __restrict__ hbe2,
    float* __restrict__ favg, float* __restrict__ h1m,
    float* __restrict__ amean) {
  __shared__ __attribute__((aligned(16))) float S[12800];  // 51.2 KB
  const int blk = blockIdx.x;
  const int tid = threadIdx.x;
  const int wave = tid >> 6, lane = tid & 63;

  if (blk < 10) {
    const int d0 = blk * 64;
#pragma unroll
    for (int i = 0; i < 10; i++) S[i * 256 + tid] = h1[i * 256 + tid];
#pragma unroll
    for (int c = 0; c < 10; c++) {
      int e = c * 256 + tid;
      int row = e >> 4, col16 = e & 15;
      gl_lds16((const char*)aw2 + (size_t)row * D_DIM * 4 + d0 * 4 + col16 * 16,
               (char*)&S[2560] + e * 16);
    }
    __syncthreads();

    const int d = tid & 63, kg = tid >> 6;
    float a0 = 0.f, a1 = 0.f, a2 = 0.f, a3 = 0.f;
#pragma unroll 8
    for (int j = 0; j < 160; j++) {
      float w = S[2560 + j * 64 + d];
      a0 += S[(kg * 4 + 0) * 160 + j] * w;
      a1 += S[(kg * 4 + 1) * 160 + j] * w;
      a2 += S[(kg * 4 + 2) * 160 + j] * w;
      a3 += S[(kg * 4 + 3) * 160 + j] * w;
    }
    float p = fmaxf(a0, 0.f) + fmaxf(a1, 0.f) + fmaxf(a2, 0.f) + fmaxf(a3, 0.f);
    __syncthreads();
    S[kg * 64 + d] = p;
    __syncthreads();
    if (kg == 0)
      favg[d0 + d] = (S[d] + S[64 + d] + S[128 + d] + S[192 + d]) * (1.f / 16.f);
    return;
  }

  const int bO = (blk - 10) * 8;
  for (int e = tid; e < 8 * P_DIM; e += 256) {
    int row = bO * P_DIM + e;
    float mx = key2f(rowmax[row]);
    S[e] = 0.5f * (1.f - mx * qinv[row]);
  }
  __syncthreads();

#pragma unroll
  for (int i = 0; i < 2; i++) {
    int b = wave * 2 + i;
    float s = S[b * P_DIM + lane];
    s += S[b * P_DIM + lane + 64];
    s += S[b * P_DIM + lane + 128];
    if (lane < 33) s += S[b * P_DIM + lane + 192];
#pragma unroll
    for (int off = 32; off > 0; off >>= 1) s += __shfl_xor(s, off);
    if (lane == 0) amean[bO + b] = s * (1.f / 225.f);
  }

  const int j = tid & 127, bh = tid >> 7;
  float acc[4];
#pragma unroll
  for (int bb = 0; bb < 4; bb++) acc[bb] = hb1[j];

  for (int t = 0; t < 7; t++) {
    int p0 = t * 32;
#pragma unroll
    for (int c = 0; c < 4; c++) {
      int e = c * 256 + tid;
      int row = e >> 5, col16 = e & 31;
      gl_lds16((const char*)hw1 + (size_t)(p0 + row) * 128 * 4 + col16 * 16,
               (char*)&S[1800] + e * 16);
    }
    __syncthreads();
#pragma unroll 4
    for (int pr = 0; pr < 32; pr++) {
      float w = S[1800 + pr * 128 + j];
#pragma unroll
      for (int bb = 0; bb < 4; bb++)
        acc[bb] += S[(bh * 4 + bb) * P_DIM + p0 + pr] * w;
    }
    __syncthreads();
  }
  {
    float w = hw1[224 * 128 + j];
#pragma unroll
    for (int bb = 0; bb < 4; bb++)
      acc[bb] += S[(bh * 4 + bb) * P_DIM + 224] * w;
  }
#pragma unroll
  for (int bb = 0; bb < 4; bb++) {
    float h = fmaxf(acc[bb], 0.f) * hg2[j] + hbe2[j];
    h1m[(bO + bh * 4 + bb) * 128 + j] = h;
  }
}

// =====================================================================
// Kernel T2: tail part 2 (unchanged).
// =====================================================================
__global__ __launch_bounds__(256) void tail2_kernel(
    const float* __restrict__ q_img, const float* __restrict__ favg,
    const float* __restrict__ h1m, const float* __restrict__ amean,
    const float* __restrict__ hw2, const float* __restrict__ hb2,
    const float* __restrict__ hg3, const float* __restrict__ hbe3,
    const float* __restrict__ hw3, const float* __restrict__ hb3,
    const float* __restrict__ rw1, const float* __restrict__ rb1,
    const float* __restrict__ rg2, const float* __restrict__ rbe2,
    const float* __restrict__ rw2, const float* __restrict__ rb2,
    const float* __restrict__ rg3, const float* __restrict__ rbe3,
    const float* __restrict__ rw3, const float* __restrict__ rb3,
    float* __restrict__ out) {
  __shared__ __attribute__((aligned(16))) float S[14336];  // 57.3 KB
  const int tid = threadIdx.x;
  const int wave = tid >> 6, lane = tid & 63;
  const int bO = blockIdx.x * 8;

#pragma unroll
  for (int i = 0; i < 20; i++) {
    int e = i * 256 + tid;
    int d = e % D_DIM;
    S[e] = q_img[bO * D_DIM + e] - favg[d];
  }

#pragma unroll
  for (int c = 0; c < 4; c++) {
    int e = c * 256 + tid;
    int row = e >> 5, col16 = e & 31;
    gl_lds16((const char*)rw1 + (size_t)row * 128 * 4 + col16 * 16,
             (char*)&S[5120] + e * 16);
  }
  __syncthreads();

  const int j = tid & 127, bh = tid >> 7;
  float acc[4];
#pragma unroll
  for (int bb = 0; bb < 4; bb++) acc[bb] = rb1[j];

  for (int t = 0; t < 20; t++) {
    int bufC = 5120 + (t & 1) * 4096;
    int bufN = 5120 + ((t + 1) & 1) * 4096;
    if (t < 19) {
      int d0n = (t + 1) * 32;
#pragma unroll
      for (int c = 0; c < 4; c++) {
        int e = c * 256 + tid;
        int row = e >> 5, col16 = e & 31;
        gl_lds16((const char*)rw1 + (size_t)(d0n + row) * 128 * 4 + col16 * 16,
                 (char*)&S[bufN] + e * 16);
      }
    }
    int d0 = t * 32;
#pragma unroll 4
    for (int dr = 0; dr < 32; dr++) {
      float w = S[bufC + dr * 128 + j];
#pragma unroll
      for (int bb = 0; bb < 4; bb++)
        acc[bb] += S[(bh * 4 + bb) * D_DIM + d0 + dr] * w;
    }
    __syncthreads();
  }

#pragma unroll
  for (int bb = 0; bb < 4; bb++) {
    float h = fmaxf(acc[bb], 0.f) * rg2[j] + rbe2[j];
    S[13312 + (bh * 4 + bb) * 128 + j] = h;
  }
  __syncthreads();

#pragma unroll
  for (int c = 0; c < 8; c++) {
    int e = c * 256 + tid;
    gl_lds16((const char*)rw2 + e * 16, (char*)&S[0] + e * 16);
  }
#pragma unroll
  for (int i = 0; i < 4; i++) {
    int e = i * 256 + tid;
    S[8192 + e] = h1m[bO * 128 + e];
  }
  __syncthreads();

  {
    const int n = tid & 63, bg = tid >> 6;
#pragma unroll
    for (int bb = 0; bb < 2; bb++) {
      int b = bg * 2 + bb;
      float a = rb2[n];
#pragma unroll 8
      for (int jj = 0; jj < 128; jj++) a += S[13312 + b * 128 + jj] * S[jj * 64 + n];
      S[10240 + b * 64 + n] = fmaxf(a, 0.f) * rg3[n] + rbe3[n];
    }
  }
  __syncthreads();

#pragma unroll
  for (int c = 0; c < 8; c++) {
    int e = c * 256 + tid;
    gl_lds16((const char*)hw2 + e * 16, (char*)&S[0] + e * 16);
  }

#pragma unroll
  for (int i = 0; i < 2; i++) {
    int b = wave * 2 + i;
    float v = S[10240 + b * 64 + lane] * rw3[lane];
#pragma unroll
    for (int off = 32; off > 0; off >>= 1) v += __shfl_xor(v, off);
    if (lane == 0) S[11264 + b] = sigmoidf(v + rb3[0]);
  }
  __syncthreads();

  {
    const int n = tid & 63, bg = tid >> 6;
#pragma unroll
    for (int bb = 0; bb < 2; bb++) {
      int b = bg * 2 + bb;
      float a = hb2[n];
#pragma unroll 8
      for (int jj = 0; jj < 128; jj++) a += S[8192 + b * 128 + jj] * S[jj * 64 + n];
      S[10752 + b * 64 + n] = fmaxf(a, 0.f) * hg3[n] + hbe3[n];
    }
  }
  __syncthreads();

#pragma unroll
  for (int i = 0; i < 2; i++) {
    int b = wave * 2 + i;
    float v = S[10752 + b * 64 + lane] * hw3[lane];
#pragma unroll
    for (int off = 32; off > 0; off >>= 1) v += __shfl_xor(v, off);
    if (lane == 0) S[11272 + b] = sigmoidf(v + hb3[0]);
  }
  __syncthreads();

  if (tid < 8) {
    int b = bO + tid;
    out[b] = 0.5f * (S[11264 + tid] + S[11272 + tid]) + amean[b];
  }
}

// ---------------- launch ----------------
extern "C" void kernel_launch(void* const* d_in, const int* in_sizes, int n_in,
                              void* d_out, int out_size, void* d_ws, size_t ws_size,
                              hipStream_t stream) {
  const float* q_patch = (const float*)d_in[0];
  const float* r_patch = (const float*)d_in[1];
  const float* q_img   = (const float*)d_in[2];
  const float* r_img   = (const float*)d_in[3];
  const float* adpt_w1 = (const float*)d_in[4];
  const float* adpt_w2 = (const float*)d_in[5];
  const float* dh_w1 = (const float*)d_in[6];
  const float* dh_b1 = (const float*)d_in[7];
  const float* dh_g2 = (const float*)d_in[8];
  const float* dh_be2 = (const float*)d_in[9];
  const float* dh_w2 = (const float*)d_in[10];
  const float* dh_b2 = (const float*)d_in[11];
  const float* dh_g3 = (const float*)d_in[12];
  const float* dh_be3 = (const float*)d_in[13];
  const float* dh_w3 = (const float*)d_in[14];
  const float* dh_b3 = (const float*)d_in[15];
  const float* dr_w1 = (const float*)d_in[16];
  const float* dr_b1 = (const float*)d_in[17];
  const float* dr_g2 = (const float*)d_in[18];
  const float* dr_be2 = (const float*)d_in[19];
  const float* dr_w2 = (const float*)d_in[20];
  const float* dr_b2 = (const float*)d_in[21];
  const float* dr_g3 = (const float*)d_in[22];
  const float* dr_be3 = (const float*)d_in[23];
  const float* dr_w3 = (const float*)d_in[24];
  const float* dr_b3 = (const float*)d_in[25];

  // ws layout (bytes) — fp8 staging buffers
  const size_t QB_BYTES = (size_t)MPAD * D_DIM;   // 9,256,960
  const size_t RB_BYTES = (size_t)NPAD * D_DIM;   // 2,375,680
  char* ws = (char*)d_ws;
  unsigned char* qb = (unsigned char*)(ws);
  unsigned char* rb = (unsigned char*)(ws + QB_BYTES);
  float* qinv        = (float*)(ws + QB_BYTES + RB_BYTES);
  unsigned* rowmax   = (unsigned*)(ws + QB_BYTES + RB_BYTES + (size_t)M_REAL * 4);
  float* h1          = (float*)(ws + QB_BYTES + RB_BYTES + (size_t)M_REAL * 4 + (size_t)MPAD * 4);
  float* favg        = h1 + 16 * 160;
  float* h1m         = favg + D_DIM;
  float* amean       = h1m + 64 * 128;

  stage_all_kernel<<<ABLKS + QBLKS + RBLKS, 256, 0, stream>>>(
      q_patch, r_patch, r_img, adpt_w1, qb, rb, qinv, rowmax, h1);
  sim_max_kernel<<<8 * MCHUNK * NTILES, 256, 0, stream>>>(qb, rb, rowmax);
  tail1_kernel<<<18, 256, 0, stream>>>(
      h1, adpt_w2, rowmax, qinv, dh_w1, dh_b1, dh_g2, dh_be2,
      favg, h1m, amean);
  tail2_kernel<<<8, 256, 0, stream>>>(
      q_img, favg, h1m, amean,
      dh_w2, dh_b2, dh_g3, dh_be3, dh_w3, dh_b3,
      dr_w1, dr_b1, dr_g2, dr_be2, dr_w2, dr_b2, dr_g3, dr_be3, dr_w3, dr_b3,
      (float*)d_out);
}

// Round 11
// 281.457 us; speedup vs baseline: 1.3693x; 1.0317x over previous
//
#include <hip/hip_runtime.h>
#include <stdint.h>

// ---------------- problem dims ----------------
#define B_DIM 64
#define P_DIM 225
#define K_DIM 16
#define D_DIM 640
#define M_REAL (B_DIM * P_DIM)   // 14400 query rows
#define N_REAL (K_DIM * P_DIM)   // 3600 reference rows

// ---------------- GEMM tiling ----------------
#define BM 128
#define BN 128
#define MTILES 113               // ceil(14400/128) -> Mpad 14464
#define NTILES 29                // ceil(3600/128)  -> Npad 3712
#define MPAD (MTILES * BM)
#define NPAD (NTILES * BN)
#define MCHUNK 15                // ceil(MTILES/8) per-XCD bm groups

typedef float f32x4 __attribute__((ext_vector_type(4)));

// ---------------- helpers ----------------
// float -> OCP e4m3 byte (v_cvt_pk_fp8_f32)
__device__ __forceinline__ unsigned char f2fp8(float f) {
  int r = __builtin_amdgcn_cvt_pk_fp8_f32(f, f, 0, false);
  return (unsigned char)(r & 0xFF);
}

// monotone float -> uint key (order-preserving), for atomicMax on floats
__device__ __forceinline__ unsigned f2key(float f) {
  union { float f; unsigned u; } v; v.f = f;
  unsigned u = v.u;
  return (u & 0x80000000u) ? ~u : (u | 0x80000000u);
}
__device__ __forceinline__ float key2f(unsigned k) {
  unsigned b = (k & 0x80000000u) ? (k ^ 0x80000000u) : ~k;
  union { unsigned u; float f; } v; v.u = b;
  return v.f;
}

__device__ __forceinline__ void gl_lds16(const void* g, void* l) {
  __builtin_amdgcn_global_load_lds(
      (const __attribute__((address_space(1))) void*)g,
      (__attribute__((address_space(3))) void*)l,
      16, 0, 0);
}

__device__ __forceinline__ float sigmoidf(float x) {
  return 1.f / (1.f + expf(-x));
}

// =====================================================================
// Kernel A: staging (fp8 e4m3 outputs) — unchanged from round 8/10
// =====================================================================
#define QBLKS (MPAD / 4)
#define RBLKS (NPAD / 4)
#define ABLKS 16
__global__ __launch_bounds__(256) void stage_all_kernel(
    const float* __restrict__ q, const float* __restrict__ r,
    const float* __restrict__ r_img, const float* __restrict__ aw1,
    unsigned char* __restrict__ qb, unsigned char* __restrict__ rb,
    float* __restrict__ qinv, unsigned* __restrict__ rowmax,
    float* __restrict__ h1) {
  const int blk = blockIdx.x;
  const int tid = threadIdx.x;

  if (blk < ABLKS) {
    __shared__ float rk_s[D_DIM];
    const int k = blk;
    for (int i = tid; i < D_DIM; i += 256) rk_s[i] = r_img[k * D_DIM + i];
    __syncthreads();
    if (tid < 160) {
      const int j = tid;
      float a = 0.f;
#pragma unroll 8
      for (int d = 0; d < D_DIM; d++) a += rk_s[d] * aw1[d * 160 + j];
      h1[k * 160 + j] = fmaxf(a, 0.f);
    }
    return;
  }

  if (blk < ABLKS + QBLKS) {
    int row = (blk - ABLKS) * 4 + (tid >> 6);
    int lane = tid & 63;
    if (lane == 0) rowmax[row] = 0u;
    unsigned char* dst = qb + (long)row * D_DIM;
    if (row >= M_REAL) {
#pragma unroll
      for (int i = 0; i < 10; i++) dst[i * 64 + lane] = 0;
      return;
    }
    const float* src = q + (long)row * D_DIM;
    float v[10];
    float ss = 0.f;
#pragma unroll
    for (int i = 0; i < 10; i++) { v[i] = src[i * 64 + lane]; ss += v[i] * v[i]; }
#pragma unroll
    for (int off = 32; off > 0; off >>= 1) ss += __shfl_xor(ss, off);
    float inv = 1.f / (sqrtf(ss) + 1e-6f);
    if (lane == 0) qinv[row] = inv * (1.f / 16.f);  // fold r-scale
#pragma unroll
    for (int i = 0; i < 10; i++) dst[i * 64 + lane] = f2fp8(v[i]);
    return;
  }

  {
    int row = (blk - ABLKS - QBLKS) * 4 + (tid >> 6);
    int lane = tid & 63;
    unsigned char* dst = rb + (long)row * D_DIM;
    if (row >= N_REAL) {
#pragma unroll
      for (int i = 0; i < 10; i++) dst[i * 64 + lane] = 0;
      return;
    }
    const float* src = r + (long)row * D_DIM;
    float v[10];
    float ss = 0.f;
#pragma unroll
    for (int i = 0; i < 10; i++) { v[i] = src[i * 64 + lane]; ss += v[i] * v[i]; }
#pragma unroll
    for (int off = 32; off > 0; off >>= 1) ss += __shfl_xor(ss, off);
    float sc = 16.f / (sqrtf(ss) + 1e-6f);   // normalize, x16 into e4m3 normals
#pragma unroll
    for (int i = 0; i < 10; i++) dst[i * 64 + lane] = f2fp8(v[i] * sc);
  }
}

// =====================================================================
// Kernel B: fused fp8 MFMA GEMM + row-max, chunk-planar LDS layout,
//   BK=128 as FOUR K=32 sub-tiles (round-8 geometry per sub-tile).
//   Halves barrier count vs round 8 (5 K-iters, 64 MFMA per barrier
//   pair) to amortize the vmcnt(0) drain; LDS 16->32 KB (5 blocks/CU).
//   Frag read bank = (4*m0 + 2*h8) mod 32 -> all 32 banks, 2-way (free).
// =====================================================================
__global__ __launch_bounds__(256) void sim_max_kernel(
    const unsigned char* __restrict__ Qb,
    const unsigned char* __restrict__ Rb,
    unsigned* __restrict__ rowmax) {
  __shared__ __attribute__((aligned(16))) unsigned char As[4][BM * 32];  // 4x4 KB
  __shared__ __attribute__((aligned(16))) unsigned char Bs[4][BN * 32];  // 4x4 KB

  const int xcd = blockIdx.x & 7;
  const int idx = blockIdx.x >> 3;
  const int bm = xcd + 8 * (idx % MCHUNK);
  const int bn = idx / MCHUNK;
  if (bm >= MTILES) return;

  const int tid = threadIdx.x;
  const int wave = tid >> 6, lane = tid & 63;
  const int wr = wave >> 1, wc = wave & 1;
  const int q = lane >> 4, m0 = lane & 15;
  const int cq = q >> 1, h8 = q & 1;   // 16-B chunk + 8-B half of frag

  // ---- staging geometry (chunk-planar, per sub-tile): slot s = tid ----
  const int rS = ((tid >> 5) << 4) | (tid & 15);
  const int cS = (tid >> 4) & 1;
  const int f = tid * 16;              // LDS byte (contiguous, lane*16)

  // ---- frag read LDS byte offsets (within As[h]/Bs[h]) ----
  const int aG = wr * 4, bG = wc * 4;  // group base per wave
  const int fragBase = (cq * 16 + m0) * 16 + h8 * 8;

  const int aBase = bm * BM;
  const int bBase = bn * BN;

  f32x4 zero = {0.f, 0.f, 0.f, 0.f};
  f32x4 acc[4][4];
#pragma unroll
  for (int i = 0; i < 4; i++)
#pragma unroll
    for (int j = 0; j < 4; j++) acc[i][j] = zero;

  for (int k0 = 0; k0 < D_DIM; k0 += 128) {   // 5 iterations
#pragma unroll
    for (int h = 0; h < 4; h++) {
      gl_lds16(Qb + (size_t)(aBase + rS) * D_DIM + k0 + h * 32 + cS * 16, &As[h][f]);
      gl_lds16(Rb + (size_t)(bBase + rS) * D_DIM + k0 + h * 32 + cS * 16, &Bs[h][f]);
    }
    __syncthreads();  // drains vmcnt -> all four LDS sub-tiles ready

#pragma unroll
    for (int h = 0; h < 4; h++) {
      long af[4], bfr[4];
#pragma unroll
      for (int mi = 0; mi < 4; mi++)
        af[mi] = *(const long*)&As[h][(aG + mi) * 512 + fragBase];
#pragma unroll
      for (int ni = 0; ni < 4; ni++)
        bfr[ni] = *(const long*)&Bs[h][(bG + ni) * 512 + fragBase];
#pragma unroll
      for (int mi = 0; mi < 4; mi++)
#pragma unroll
        for (int ni = 0; ni < 4; ni++)
          acc[mi][ni] = __builtin_amdgcn_mfma_f32_16x16x32_fp8_fp8(
              af[mi], bfr[ni], acc[mi][ni], 0, 0, 0);
    }
    __syncthreads();  // protect LDS before next-iter overwrite
  }

  // epilogue: per-row max over this block's 128 columns, then global atomicMax
  const int colBase = bn * BN + wc * 64;
#pragma unroll
  for (int mi = 0; mi < 4; mi++) {
    float rmax[4] = {-3.0e38f, -3.0e38f, -3.0e38f, -3.0e38f};
#pragma unroll
    for (int ni = 0; ni < 4; ni++) {
      bool valid = (colBase + ni * 16 + m0) < N_REAL;
#pragma unroll
      for (int r = 0; r < 4; r++) {
        float v = valid ? acc[mi][ni][r] : -3.0e38f;
        rmax[r] = fmaxf(rmax[r], v);
      }
    }
#pragma unroll
    for (int r = 0; r < 4; r++) {
      float v = rmax[r];
      v = fmaxf(v, __shfl_xor(v, 1));
      v = fmaxf(v, __shfl_xor(v, 2));
      v = fmaxf(v, __shfl_xor(v, 4));
      v = fmaxf(v, __shfl_xor(v, 8));
      rmax[r] = v;
    }
    if (m0 == 0) {
      int row = bm * BM + wr * 64 + mi * 16 + q * 4;
#pragma unroll
      for (int r = 0; r < 4; r++)
        atomicMax(&rowmax[row + r], f2key(rmax[r]));
    }
  }
}

// =====================================================================
// Kernel T1: tail part 1 (unchanged).
// =====================================================================
__global__ __launch_bounds__(256) void tail1_kernel(
    const float* __restrict__ h1, const float* __restrict__ aw2,
    const unsigned* __restrict__ rowmax, const float* __restrict__ qinv,
    const float* __restrict__ hw1, const float* __restrict__ hb1,
    const float* __restrict__ hg2, const float* __restrict__ hbe2,
    float* __restrict__ favg, float* __restrict__ h1m,
    float* __restrict__ amean) {
  __shared__ __attribute__((aligned(16))) float S[12800];  // 51.2 KB
  const int blk = blockIdx.x;
  const int tid = threadIdx.x;
  const int wave = tid >> 6, lane = tid & 63;

  if (blk < 10) {
    const int d0 = blk * 64;
#pragma unroll
    for (int i = 0; i < 10; i++) S[i * 256 + tid] = h1[i * 256 + tid];
#pragma unroll
    for (int c = 0; c < 10; c++) {
      int e = c * 256 + tid;
      int row = e >> 4, col16 = e & 15;
      gl_lds16((const char*)aw2 + (size_t)row * D_DIM * 4 + d0 * 4 + col16 * 16,
               (char*)&S[2560] + e * 16);
    }
    __syncthreads();

    const int d = tid & 63, kg = tid >> 6;
    float a0 = 0.f, a1 = 0.f, a2 = 0.f, a3 = 0.f;
#pragma unroll 8
    for (int j = 0; j < 160; j++) {
      float w = S[2560 + j * 64 + d];
      a0 += S[(kg * 4 + 0) * 160 + j] * w;
      a1 += S[(kg * 4 + 1) * 160 + j] * w;
      a2 += S[(kg * 4 + 2) * 160 + j] * w;
      a3 += S[(kg * 4 + 3) * 160 + j] * w;
    }
    float p = fmaxf(a0, 0.f) + fmaxf(a1, 0.f) + fmaxf(a2, 0.f) + fmaxf(a3, 0.f);
    __syncthreads();
    S[kg * 64 + d] = p;
    __syncthreads();
    if (kg == 0)
      favg[d0 + d] = (S[d] + S[64 + d] + S[128 + d] + S[192 + d]) * (1.f / 16.f);
    return;
  }

  const int bO = (blk - 10) * 8;
  for (int e = tid; e < 8 * P_DIM; e += 256) {
    int row = bO * P_DIM + e;
    float mx = key2f(rowmax[row]);
    S[e] = 0.5f * (1.f - mx * qinv[row]);
  }
  __syncthreads();

#pragma unroll
  for (int i = 0; i < 2; i++) {
    int b = wave * 2 + i;
    float s = S[b * P_DIM + lane];
    s += S[b * P_DIM + lane + 64];
    s += S[b * P_DIM + lane + 128];
    if (lane < 33) s += S[b * P_DIM + lane + 192];
#pragma unroll
    for (int off = 32; off > 0; off >>= 1) s += __shfl_xor(s, off);
    if (lane == 0) amean[bO + b] = s * (1.f / 225.f);
  }

  const int j = tid & 127, bh = tid >> 7;
  float acc[4];
#pragma unroll
  for (int bb = 0; bb < 4; bb++) acc[bb] = hb1[j];

  for (int t = 0; t < 7; t++) {
    int p0 = t * 32;
#pragma unroll
    for (int c = 0; c < 4; c++) {
      int e = c * 256 + tid;
      int row = e >> 5, col16 = e & 31;
      gl_lds16((const char*)hw1 + (size_t)(p0 + row) * 128 * 4 + col16 * 16,
               (char*)&S[1800] + e * 16);
    }
    __syncthreads();
#pragma unroll 4
    for (int pr = 0; pr < 32; pr++) {
      float w = S[1800 + pr * 128 + j];
#pragma unroll
      for (int bb = 0; bb < 4; bb++)
        acc[bb] += S[(bh * 4 + bb) * P_DIM + p0 + pr] * w;
    }
    __syncthreads();
  }
  {
    float w = hw1[224 * 128 + j];
#pragma unroll
    for (int bb = 0; bb < 4; bb++)
      acc[bb] += S[(bh * 4 + bb) * P_DIM + 224] * w;
  }
#pragma unroll
  for (int bb = 0; bb < 4; bb++) {
    float h = fmaxf(acc[bb], 0.f) * hg2[j] + hbe2[j];
    h1m[(bO + bh * 4 + bb) * 128 + j] = h;
  }
}

// =====================================================================
// Kernel T2: tail part 2 (unchanged).
// =====================================================================
__global__ __launch_bounds__(256) void tail2_kernel(
    const float* __restrict__ q_img, const float* __restrict__ favg,
    const float* __restrict__ h1m, const float* __restrict__ amean,
    const float* __restrict__ hw2, const float* __restrict__ hb2,
    const float* __restrict__ hg3, const float* __restrict__ hbe3,
    const float* __restrict__ hw3, const float* __restrict__ hb3,
    const float* __restrict__ rw1, const float* __restrict__ rb1,
    const float* __restrict__ rg2, const float* __restrict__ rbe2,
    const float* __restrict__ rw2, const float* __restrict__ rb2,
    const float* __restrict__ rg3, const float* __restrict__ rbe3,
    const float* __restrict__ rw3, const float* __restrict__ rb3,
    float* __restrict__ out) {
  __shared__ __attribute__((aligned(16))) float S[14336];  // 57.3 KB
  const int tid = threadIdx.x;
  const int wave = tid >> 6, lane = tid & 63;
  const int bO = blockIdx.x * 8;

#pragma unroll
  for (int i = 0; i < 20; i++) {
    int e = i * 256 + tid;
    int d = e % D_DIM;
    S[e] = q_img[bO * D_DIM + e] - favg[d];
  }

#pragma unroll
  for (int c = 0; c < 4; c++) {
    int e = c * 256 + tid;
    int row = e >> 5, col16 = e & 31;
    gl_lds16((const char*)rw1 + (size_t)row * 128 * 4 + col16 * 16,
             (char*)&S[5120] + e * 16);
  }
  __syncthreads();

  const int j = tid & 127, bh = tid >> 7;
  float acc[4];
#pragma unroll
  for (int bb = 0; bb < 4; bb++) acc[bb] = rb1[j];

  for (int t = 0; t < 20; t++) {
    int bufC = 5120 + (t & 1) * 4096;
    int bufN = 5120 + ((t + 1) & 1) * 4096;
    if (t < 19) {
      int d0n = (t + 1) * 32;
#pragma unroll
      for (int c = 0; c < 4; c++) {
        int e = c * 256 + tid;
        int row = e >> 5, col16 = e & 31;
        gl_lds16((const char*)rw1 + (size_t)(d0n + row) * 128 * 4 + col16 * 16,
                 (char*)&S[bufN] + e * 16);
      }
    }
    int d0 = t * 32;
#pragma unroll 4
    for (int dr = 0; dr < 32; dr++) {
      float w = S[bufC + dr * 128 + j];
#pragma unroll
      for (int bb = 0; bb < 4; bb++)
        acc[bb] += S[(bh * 4 + bb) * D_DIM + d0 + dr] * w;
    }
    __syncthreads();
  }

#pragma unroll
  for (int bb = 0; bb < 4; bb++) {
    float h = fmaxf(acc[bb], 0.f) * rg2[j] + rbe2[j];
    S[13312 + (bh * 4 + bb) * 128 + j] = h;
  }
  __syncthreads();

#pragma unroll
  for (int c = 0; c < 8; c++) {
    int e = c * 256 + tid;
    gl_lds16((const char*)rw2 + e * 16, (char*)&S[0] + e * 16);
  }
#pragma unroll
  for (int i = 0; i < 4; i++) {
    int e = i * 256 + tid;
    S[8192 + e] = h1m[bO * 128 + e];
  }
  __syncthreads();

  {
    const int n = tid & 63, bg = tid >> 6;
#pragma unroll
    for (int bb = 0; bb < 2; bb++) {
      int b = bg * 2 + bb;
      float a = rb2[n];
#pragma unroll 8
      for (int jj = 0; jj < 128; jj++) a += S[13312 + b * 128 + jj] * S[jj * 64 + n];
      S[10240 + b * 64 + n] = fmaxf(a, 0.f) * rg3[n] + rbe3[n];
    }
  }
  __syncthreads();

#pragma unroll
  for (int c = 0; c < 8; c++) {
    int e = c * 256 + tid;
    gl_lds16((const char*)hw2 + e * 16, (char*)&S[0] + e * 16);
  }

#pragma unroll
  for (int i = 0; i < 2; i++) {
    int b = wave * 2 + i;
    float v = S[10240 + b * 64 + lane] * rw3[lane];
#pragma unroll
    for (int off = 32; off > 0; off >>= 1) v += __shfl_xor(v, off);
    if (lane == 0) S[11264 + b] = sigmoidf(v + rb3[0]);
  }
  __syncthreads();

  {
    const int n = tid & 63, bg = tid >> 6;
#pragma unroll
    for (int bb = 0; bb < 2; bb++) {
      int b = bg * 2 + bb;
      float a = hb2[n];
#pragma unroll 8
      for (int jj = 0; jj < 128; jj++) a += S[8192 + b * 128 + jj] * S[jj * 64 + n];
      S[10752 + b * 64 + n] = fmaxf(a, 0.f) * hg3[n] + hbe3[n];
    }
  }
  __syncthreads();

#pragma unroll
  for (int i = 0; i < 2; i++) {
    int b = wave * 2 + i;
    float v = S[10752 + b * 64 + lane] * hw3[lane];
#pragma unroll
    for (int off = 32; off > 0; off >>= 1) v += __shfl_xor(v, off);
    if (lane == 0) S[11272 + b] = sigmoidf(v + hb3[0]);
  }
  __syncthreads();

  if (tid < 8) {
    int b = bO + tid;
    out[b] = 0.5f * (S[11264 + tid] + S[11272 + tid]) + amean[b];
  }
}

// ---------------- launch ----------------
extern "C" void kernel_launch(void* const* d_in, const int* in_sizes, int n_in,
                              void* d_out, int out_size, void* d_ws, size_t ws_size,
                              hipStream_t stream) {
  const float* q_patch = (const float*)d_in[0];
  const float* r_patch = (const float*)d_in[1];
  const float* q_img   = (const float*)d_in[2];
  const float* r_img   = (const float*)d_in[3];
  const float* adpt_w1 = (const float*)d_in[4];
  const float* adpt_w2 = (const float*)d_in[5];
  const float* dh_w1 = (const float*)d_in[6];
  const float* dh_b1 = (const float*)d_in[7];
  const float* dh_g2 = (const float*)d_in[8];
  const float* dh_be2 = (const float*)d_in[9];
  const float* dh_w2 = (const float*)d_in[10];
  const float* dh_b2 = (const float*)d_in[11];
  const float* dh_g3 = (const float*)d_in[12];
  const float* dh_be3 = (const float*)d_in[13];
  const float* dh_w3 = (const float*)d_in[14];
  const float* dh_b3 = (const float*)d_in[15];
  const float* dr_w1 = (const float*)d_in[16];
  const float* dr_b1 = (const float*)d_in[17];
  const float* dr_g2 = (const float*)d_in[18];
  const float* dr_be2 = (const float*)d_in[19];
  const float* dr_w2 = (const float*)d_in[20];
  const float* dr_b2 = (const float*)d_in[21];
  const float* dr_g3 = (const float*)d_in[22];
  const float* dr_be3 = (const float*)d_in[23];
  const float* dr_w3 = (const float*)d_in[24];
  const float* dr_b3 = (const float*)d_in[25];

  // ws layout (bytes) — fp8 staging buffers
  const size_t QB_BYTES = (size_t)MPAD * D_DIM;   // 9,256,960
  const size_t RB_BYTES = (size_t)NPAD * D_DIM;   // 2,375,680
  char* ws = (char*)d_ws;
  unsigned char* qb = (unsigned char*)(ws);
  unsigned char* rb = (unsigned char*)(ws + QB_BYTES);
  float* qinv        = (float*)(ws + QB_BYTES + RB_BYTES);
  unsigned* rowmax   = (unsigned*)(ws + QB_BYTES + RB_BYTES + (size_t)M_REAL * 4);
  float* h1          = (float*)(ws + QB_BYTES + RB_BYTES + (size_t)M_REAL * 4 + (size_t)MPAD * 4);
  float* favg        = h1 + 16 * 160;
  float* h1m         = favg + D_DIM;
  float* amean       = h1m + 64 * 128;

  stage_all_kernel<<<ABLKS + QBLKS + RBLKS, 256, 0, stream>>>(
      q_patch, r_patch, r_img, adpt_w1, qb, rb, qinv, rowmax, h1);
  sim_max_kernel<<<8 * MCHUNK * NTILES, 256, 0, stream>>>(qb, rb, rowmax);
  tail1_kernel<<<18, 256, 0, stream>>>(
      h1, adpt_w2, rowmax, qinv, dh_w1, dh_b1, dh_g2, dh_be2,
      favg, h1m, amean);
  tail2_kernel<<<8, 256, 0, stream>>>(
      q_img, favg, h1m, amean,
      dh_w2, dh_b2, dh_g3, dh_be3, dh_w3, dh_b3,
      dr_w1, dr_b1, dr_g2, dr_be2, dr_w2, dr_b2, dr_g3, dr_be3, dr_w3, dr_b3,
      (float*)d_out);
}